// Round 11
// baseline (346.003 us; speedup 1.0000x reference)
//
#include <hip/hip_runtime.h>
#include <cstddef>

// ---------------------------------------------------------------------------
// Fused attention block for MI355X (gfx950), FP16 MFMA pipeline.
// B=32, S=256, DIM=2048, NH=16, NKV=16, HD=128, GRID=16, BASE=10000, CLS=1.
//
// Pipeline:
//   1. cvt3: x, wqkv, wo  f32 -> f16 (single kernel)
//   2. gemm_bt5: qkv = x @ wqkv^T          (8192x6144x2048, f16 out)
//   3. attn: causal flash attention, FUSED 2D-RoPE on Q (regs) and K
//      (staging); V staged row-major via async gload16 and consumed through
//      ds_read_b64_tr_b16 (HW transpose)  -> O f16 (8192 x 2048)
//   4. gemm_bt5: out = O @ wo^T            (8192x2048x2048, f32 out)
//
// gemm_bt5 (R10: gates reduced to 2/tile, m201 cadence): 256x256 tile,
// BK=64, 8 waves (2m x 4n), 2-deep LDS double buffer, row-split half-tiles;
// per phase: {ds_reads; stage 1 half-tile; setprio(1); MFMA x16;
// setprio(0); [vmcnt(6) at p1,p3 only]; BAR}.
// Gate audit (batch order: ...,T-1.p3:A0(T+1), T.p0:B0(T+1), T.p1:B1(T+1),
// T.p2:A1(T+1), T.p3:A0(T+2)): p3-close allows 3 newest outstanding ->
// forces B0(T+1)+A0(T+1)+older; p1-close forces A1(T)+older. Identical
// guarantee set to the 4-gate variant (p0/p2 gates forced nothing extra).
// ---------------------------------------------------------------------------

typedef float    f32x4 __attribute__((ext_vector_type(4)));
typedef _Float16 f16x8 __attribute__((ext_vector_type(8)));
typedef _Float16 f16x4 __attribute__((ext_vector_type(4)));

#define LOG2E 1.4426950408889634f
#define NLOG2B_32 (-0.41524101186192697f)   // -log2(10000)/32

__device__ static inline f32x4 mfma16x32(f16x8 a, f16x8 b, f32x4 c) {
  return __builtin_amdgcn_mfma_f32_16x16x32_f16(a, b, c, 0, 0, 0);
}

// async global->LDS, 16B per lane; lds must be the wave-uniform base
// (HW dest = base + lane*16).
__device__ static inline void gload16(const void* g, void* lds) {
  __builtin_amdgcn_global_load_lds(
      (const __attribute__((address_space(1))) unsigned int*)g,
      (__attribute__((address_space(3))) unsigned int*)lds, 16, 0, 0);
}

#define BAR()    asm volatile("s_barrier" ::: "memory")
#define VMCNT6() asm volatile("s_waitcnt vmcnt(6)" ::: "memory")

// ---------------- 1. f32 -> f16 convert (three buffers, one kernel) --------
__global__ void cvt3_f32_f16(const float* __restrict__ s0, _Float16* __restrict__ d0,
                             const float* __restrict__ s1, _Float16* __restrict__ d1,
                             const float* __restrict__ s2, _Float16* __restrict__ d2) {
  int i = blockIdx.x * blockDim.x + threadIdx.x;   // quad index
  const float* src; _Float16* dst;
  if (i < 4194304)      { src = s0; dst = d0; }
  else if (i < 7340032) { src = s1; dst = d1; i -= 4194304; }
  else                  { src = s2; dst = d2; i -= 7340032; }
  f32x4 v = *(const f32x4*)(src + (size_t)i * 4);
  f16x4 o;
  o[0] = (_Float16)v[0]; o[1] = (_Float16)v[1];
  o[2] = (_Float16)v[2]; o[3] = (_Float16)v[3];
  *(f16x4*)(dst + (size_t)i * 4) = o;
}

// ---------------- 2./4. GEMM: C[m,n] = sum_k A[m,k] * Bt[n,k] ----------------
// 256x256 tile, BK=64, 8 waves (2m x 4n), 2-deep LDS double buffer.
// Per K-tile 4 phases, one C-quadrant (16 MFMA) each:
//   p0: read af0(8) bf0(4); stage B0(T+1)->nb; MFMA af0 x bf0
//   p1: read bf1(4);        stage B1(T+1)->nb; MFMA af0 x bf1; vmcnt(6)
//   p2: read af1(8);        stage A1(T+1)->nb; MFMA af1 x bf0
//   p3:                     stage A0(T+2)->cb; MFMA af1 x bf1; vmcnt(6)
// One barrier per phase; vmcnt gates at p1/p3 only (m201 cadence).
template <typename OutT>
__global__ void __launch_bounds__(512, 2)
gemm_bt5(const _Float16* __restrict__ A, const _Float16* __restrict__ Bt,
         OutT* __restrict__ C, int M, int N, int K) {
  __shared__ __attribute__((aligned(16))) _Float16 Ab[2][256 * 64];
  __shared__ __attribute__((aligned(16))) _Float16 Bb[2][256 * 64];

  const int tid  = threadIdx.x;
  const int lane = tid & 63;
  const int w    = tid >> 6;
  const int wm   = w >> 2, wn = w & 3;
  const int g    = lane >> 4, li = lane & 15;

  // T1: XCD-aware block swizzle (grid multiple of 8 for our shapes)
  const int nwg = (int)gridDim.x;
  const int cpx = nwg >> 3;
  const int bid = (int)blockIdx.x;
  const int swz = (bid & 7) * cpx + (bid >> 3);
  const int nbn = N >> 8;
  const int bm  = (swz / nbn) << 8;
  const int bn  = (swz % nbn) << 8;
  const int NT  = K >> 6;

  // ---- staging: half-tile = 128 rows x 64 cols = 1024 chunks of 16B.
  // Thread t, load j covers linear chunk L = j*512 + t  (row L>>3, phys L&7),
  // holding logical chunk (L&7)^((L>>3)&7) -> global col ((t&7)^((t>>3)&7))*8.
  const int srow = tid >> 3;                       // 0..63
  const int scol = ((tid & 7) ^ (srow & 7)) * 8;   // pre-swizzled col (elems)
  const _Float16* gA = A  + (size_t)(bm + srow) * K + scol;
  const _Float16* gB = Bt + (size_t)(bn + srow) * K + scol;
  const int sdst = w * 1024;                       // wave-uniform byte base

  auto stage = [&](const _Float16* gbase, _Float16* lbase, int h, int kt) {
    const _Float16* gp = gbase + (size_t)h * 128 * K + kt;
    char* lp = (char*)lbase + h * 16384;
#pragma unroll
    for (int j = 0; j < 2; ++j)
      gload16(gp + (size_t)j * 64 * K, lp + j * 8192 + sdst);
  };

  // frag read: logical chunk (k2*4+g) of row -> phys chunk ^(row&7)=^(li&7)
  auto rdfrag = [&](const _Float16* buf, int row, int k2) -> f16x8 {
    const int pc = ((k2 << 2) + g) ^ (li & 7);
    return *(const f16x8*)((const char*)buf + row * 128 + pc * 16);
  };

  f32x4 acc[8][4] = {};

  // ---- prologue: A0(0) B0(0) B1(0) A1(0) A0(1); wait all but newest 3 ----
  stage(gA, Ab[0], 0, 0);
  stage(gB, Bb[0], 0, 0);
  stage(gB, Bb[0], 1, 0);
  stage(gA, Ab[0], 1, 0);
  stage(gA, Ab[1], 0, (NT > 1) ? 64 : 0);
  VMCNT6();
  BAR();

  for (int T = 0; T < NT; ++T) {
    const int cb = T & 1, nb = cb ^ 1;
    const _Float16* Ac = Ab[cb];
    const _Float16* Bc = Bb[cb];
    const int ktN  = (T + 1 < NT) ? (T + 1) << 6 : 0;
    const int ktN2 = (T + 2 < NT) ? (T + 2) << 6 : 0;

    f16x8 af0[4][2], af1[4][2], bf0[2][2], bf1[2][2];

    // ---- p0: read af0+bf0; stage B0(T+1); MFMA (m0-3 x n0-1) ----
#pragma unroll
    for (int m = 0; m < 4; ++m)
#pragma unroll
      for (int k2 = 0; k2 < 2; ++k2)
        af0[m][k2] = rdfrag(Ac, wm * 128 + m * 16 + li, k2);
#pragma unroll
    for (int n = 0; n < 2; ++n)
#pragma unroll
      for (int k2 = 0; k2 < 2; ++k2)
        bf0[n][k2] = rdfrag(Bc, wn * 64 + n * 16 + li, k2);
    stage(gB, Bb[nb], 0, ktN);
    __builtin_amdgcn_s_setprio(1);
#pragma unroll
    for (int m = 0; m < 4; ++m)
#pragma unroll
      for (int n = 0; n < 2; ++n)
#pragma unroll
        for (int k2 = 0; k2 < 2; ++k2)
          acc[m][n] = mfma16x32(af0[m][k2], bf0[n][k2], acc[m][n]);
    __builtin_amdgcn_s_setprio(0);
    BAR();

    // ---- p1: read bf1; stage B1(T+1); MFMA (m0-3 x n2-3); vmcnt gate ----
#pragma unroll
    for (int n = 0; n < 2; ++n)
#pragma unroll
      for (int k2 = 0; k2 < 2; ++k2)
        bf1[n][k2] = rdfrag(Bc, wn * 64 + (n + 2) * 16 + li, k2);
    stage(gB, Bb[nb], 1, ktN);
    __builtin_amdgcn_s_setprio(1);
#pragma unroll
    for (int m = 0; m < 4; ++m)
#pragma unroll
      for (int n = 0; n < 2; ++n)
#pragma unroll
        for (int k2 = 0; k2 < 2; ++k2)
          acc[m][n + 2] = mfma16x32(af0[m][k2], bf1[n][k2], acc[m][n + 2]);
    __builtin_amdgcn_s_setprio(0);
    VMCNT6();
    BAR();

    // ---- p2: read af1; stage A1(T+1); MFMA (m4-7 x n0-1) ----
#pragma unroll
    for (int m = 0; m < 4; ++m)
#pragma unroll
      for (int k2 = 0; k2 < 2; ++k2)
        af1[m][k2] = rdfrag(Ac, wm * 128 + (m + 4) * 16 + li, k2);
    stage(gA, Ab[nb], 1, ktN);
    __builtin_amdgcn_s_setprio(1);
#pragma unroll
    for (int m = 0; m < 4; ++m)
#pragma unroll
      for (int n = 0; n < 2; ++n)
#pragma unroll
        for (int k2 = 0; k2 < 2; ++k2)
          acc[m + 4][n] = mfma16x32(af1[m][k2], bf0[n][k2], acc[m + 4][n]);
    __builtin_amdgcn_s_setprio(0);
    BAR();

    // ---- p3: stage A0(T+2)->cb (A0 last read at p2, one BAR ago); MFMA ----
    stage(gA, Ab[cb], 0, ktN2);
    __builtin_amdgcn_s_setprio(1);
#pragma unroll
    for (int m = 0; m < 4; ++m)
#pragma unroll
      for (int n = 0; n < 2; ++n)
#pragma unroll
        for (int k2 = 0; k2 < 2; ++k2)
          acc[m + 4][n + 2] = mfma16x32(af1[m][k2], bf1[n][k2], acc[m + 4][n + 2]);
    __builtin_amdgcn_s_setprio(0);
    VMCNT6();
    BAR();
  }

  asm volatile("s_waitcnt vmcnt(0)" ::: "memory");  // drain tail garbage loads

  // ---- epilogue: D row = g*4+r, col = li (m89-verified layout) ----
#pragma unroll
  for (int m = 0; m < 8; ++m)
#pragma unroll
    for (int n = 0; n < 4; ++n)
#pragma unroll
      for (int r = 0; r < 4; ++r) {
        const int row = bm + wm * 128 + m * 16 + g * 4 + r;
        const int col = bn + wn * 64 + n * 16 + li;
        C[(size_t)row * N + col] = (OutT)acc[m][n][r];
      }
}

// ---------------- 3. causal flash attention + fused 2D RoPE ----------------
// 1 block = 1 (b,h), 512 threads = 8 waves. Wave w owns q-row blocks
// (w, 15-w): balanced causal work (wall 8->6).
// RoPE fused: 512-entry LDS sincos table + ptab[256]; Q roped in regs,
// K roped during reg-staging (load -> rope -> swizzled ds_write_b128).
//   Ks: row-major [64][128], 16B chunk c at phys c^(key&7) (conflict-free).
//   Vt: row-major [64 key][128 d], SAME chunk swizzle, staged via async
//       gload16 with pre-swizzled global source; PV B-frags read through
//       ds_read_b64_tr_b16 (m156 lane-distribution model, R9-verified).
//   Ps: per-wave P round-trip (D-frag layout -> A-frag layout), stride 40.
__global__ void __launch_bounds__(512)
attn_kernel(const _Float16* __restrict__ qkv, _Float16* __restrict__ O,
            const int* __restrict__ positions) {
  const int b  = blockIdx.x >> 4;
  const int h  = blockIdx.x & 15;
  const int tb = b << 8;
  const int tid = threadIdx.x;
  const int lane = tid & 63;
  const int w = tid >> 6;
  const int g = lane >> 4, li = lane & 15;

  __shared__ __attribute__((aligned(16))) _Float16 Ks[64 * 128];
  __shared__ __attribute__((aligned(16))) _Float16 Vt[64 * 128];
  __shared__ __attribute__((aligned(16))) _Float16 Ps[8][32 * 40];
  __shared__ float2 tab[512];
  __shared__ int    ptab[256];

  // ---- rope tables: tv = tid>>5 (0..15), k2 = tid&31 ----
  {
    const float ang = (float)(tid >> 5) * exp2f((float)(tid & 31) * NLOG2B_32);
    float s, c;
    sincosf(ang, &s, &c);
    tab[tid] = make_float2(c, s);
    if (tid < 256) ptab[tid] = positions[tb + tid];
  }
  __syncthreads();

  const int qb[2]   = {w, 15 - w};
  const int qrow[2] = {qb[0] * 16, qb[1] * 16};
  const int kmax[2] = {qb[0] >> 2, qb[1] >> 2};

  // tr-read per-lane constants: li = jj*4 + cc
  const int jj = li >> 2;
  const int cc = li & 3;
  const unsigned vbase =
      (unsigned)(unsigned long long)(__attribute__((address_space(3))) _Float16*)Vt;

  // ---- load Q + rope in registers ----
  f16x8 qf[2][4];
#pragma unroll
  for (int rb = 0; rb < 2; ++rb) {
    const int pos = ptab[qrow[rb] + li];
    const int iv = (pos - 1) >> 4, jv = (pos - 1) & 15;
#pragma unroll
    for (int ks = 0; ks < 4; ++ks) {
      f16x8 v = *(const f16x8*)(qkv + (size_t)(tb + qrow[rb] + li) * 6144
                                + h * 128 + ks * 32 + g * 8);
      f16x8 o;
      if (pos == 0) {
#pragma unroll
        for (int u = 0; u < 8; ++u) o[u] = (_Float16)0.f;
      } else {
        const int tv = (ks < 2) ? iv : jv;   // d2 = ks*16+g*4+u < 32 <=> ks<2
#pragma unroll
        for (int u = 0; u < 4; ++u) {
          const float2 cs = tab[tv * 32 + ((ks * 16 + g * 4 + u) & 31)];
          const float x0 = (float)v[2 * u], x1 = (float)v[2 * u + 1];
          o[2 * u]     = (_Float16)(x0 * cs.x - x1 * cs.y);
          o[2 * u + 1] = (_Float16)(x1 * cs.x + x0 * cs.y);
        }
      }
      qf[rb][ks] = o;
    }
  }

  f32x4 oacc[2][8] = {};
  float m_r[2][4], l_r[2][4];
#pragma unroll
  for (int rb = 0; rb < 2; ++rb)
#pragma unroll
    for (int r = 0; r < 4; ++r) { m_r[rb][r] = -1e30f; l_r[rb][r] = 0.f; }

  const float scale = 0.08838834764831845f;  // 1/sqrt(128)

  for (int kt = 0; kt < 4; ++kt) {
    // ---- stage V row-major via async gload16 (pre-swizzled source) ----
#pragma unroll
    for (int i = 0; i < 2; ++i) {
      const int s = i * 512 + tid;
      const int key = s >> 4;
      const int sch = (s & 15) ^ (key & 7);
      const _Float16* gv = qkv + (size_t)(tb + kt * 64 + key) * 6144
                           + 4096 + h * 128 + sch * 8;
      gload16(gv, (char*)Vt + (i * 512 + (tid & ~63)) * 16);
    }
    // ---- stage K tile: load -> rope -> swizzled ds_write ----
#pragma unroll
    for (int i = 0; i < 2; ++i) {
      const int s = i * 512 + tid;
      const int key = s >> 4;
      const int c   = s & 15;   // logical 16B chunk (4 rope pairs)
      f16x8 v = *(const f16x8*)(qkv + (size_t)(tb + kt * 64 + key) * 6144
                                + 2048 + h * 128 + c * 8);
      const int pos = ptab[kt * 64 + key];
      f16x8 o;
      if (pos == 0) {
#pragma unroll
        for (int u = 0; u < 8; ++u) o[u] = (_Float16)0.f;
      } else {
        const int iv = (pos - 1) >> 4, jv = (pos - 1) & 15;
        const int tv = (c < 8) ? iv : jv;    // d2 = c*4+u < 32 <=> c<8
#pragma unroll
        for (int u = 0; u < 4; ++u) {
          const float2 cs = tab[tv * 32 + ((c * 4 + u) & 31)];
          const float x0 = (float)v[2 * u], x1 = (float)v[2 * u + 1];
          o[2 * u]     = (_Float16)(x0 * cs.x - x1 * cs.y);
          o[2 * u + 1] = (_Float16)(x1 * cs.x + x0 * cs.y);
        }
      }
      *(f16x8*)((char*)Ks + key * 256 + (c ^ (key & 7)) * 16) = o;
    }
    __syncthreads();   // drains vmcnt (gload16) + lgkm (ds_writes)

    const bool act[2] = {kt <= kmax[0], kt <= kmax[1]};
    if (act[0] || act[1]) {
      // ---- S = Q K^T (64 keys) ----
      f32x4 sacc[2][4] = {};
#pragma unroll
      for (int ks = 0; ks < 4; ++ks) {
        f16x8 kf[4];
#pragma unroll
        for (int cb = 0; cb < 4; ++cb) {
          const int key = cb * 16 + li;
          const int chunk = (ks * 4 + g) ^ (key & 7);
          kf[cb] = *(const f16x8*)((const char*)Ks + key * 256 + chunk * 16);
        }
#pragma unroll
        for (int rb = 0; rb < 2; ++rb)
          if (act[rb])
#pragma unroll
            for (int cb = 0; cb < 4; ++cb)
              sacc[rb][cb] = mfma16x32(qf[rb][ks], kf[cb], sacc[rb][cb]);
      }
      // ---- online softmax (wave-parallel, 16-lane-group shfl reduce) ----
#pragma unroll
      for (int rb = 0; rb < 2; ++rb) {
        if (!act[rb]) continue;
#pragma unroll
        for (int r = 0; r < 4; ++r) {
          const int q = qrow[rb] + g * 4 + r;
          float mx = -1e30f;
#pragma unroll
          for (int cb = 0; cb < 4; ++cb) {
            float sv = sacc[rb][cb][r] * scale;
            const int key = kt * 64 + cb * 16 + li;
            sv = (key <= q) ? sv : -1e30f;
            sacc[rb][cb][r] = sv;
            mx = fmaxf(mx, sv);
          }
#pragma unroll
          for (int off = 1; off < 16; off <<= 1)
            mx = fmaxf(mx, __shfl_xor(mx, off));
          const float mold = m_r[rb][r];
          const float mnew = fmaxf(mold, mx);
          const float alpha = exp2f((mold - mnew) * LOG2E);
          float rsum = 0.f;
#pragma unroll
          for (int cb = 0; cb < 4; ++cb) {
            const float pv = exp2f((sacc[rb][cb][r] - mnew) * LOG2E);
            sacc[rb][cb][r] = pv;
            rsum += pv;
          }
#pragma unroll
          for (int off = 1; off < 16; off <<= 1)
            rsum += __shfl_xor(rsum, off);
          m_r[rb][r] = mnew;
          l_r[rb][r] = l_r[rb][r] * alpha + rsum;
#pragma unroll
          for (int db = 0; db < 8; ++db)
            oacc[rb][db][r] *= alpha;
        }
      }
      // ---- O += P V, two 32-key halves; V frags via ds_read_b64_tr_b16 ----
#pragma unroll
      for (int ks2 = 0; ks2 < 2; ++ks2) {
#pragma unroll
        for (int rb = 0; rb < 2; ++rb) {
          if (!act[rb]) continue;
#pragma unroll
          for (int cbh = 0; cbh < 2; ++cbh) {
            const int cb = ks2 * 2 + cbh;
#pragma unroll
            for (int r = 0; r < 4; ++r)
              Ps[w][(rb * 16 + g * 4 + r) * 40 + cbh * 16 + li] =
                  (_Float16)sacc[rb][cb][r];
          }
        }
        asm volatile("s_waitcnt lgkmcnt(0)" ::: "memory");
        f16x8 pa[2];
#pragma unroll
        for (int rb = 0; rb < 2; ++rb)
          if (act[rb])
            pa[rb] = *(const f16x8*)(&Ps[w][(rb * 16 + li) * 40 + g * 8]);

        // V B-frags: rows ks2*32+g*8+jj (+4), d-window db*16, swizzled chunks
        f16x4 vlo[8], vhi[8];
        const int rowA = ks2 * 32 + g * 8 + jj;
        const unsigned base1 = vbase + (unsigned)(rowA * 256 + (cc & 1) * 8);
        const unsigned base2 = base1 + 4 * 256;
#pragma unroll
        for (int db = 0; db < 8; ++db) {
          const int ch = db * 2 + (cc >> 1);
          const unsigned a1 = base1 + (unsigned)((ch ^ jj) << 4);
          const unsigned a2 = base2 + (unsigned)((ch ^ jj ^ 4) << 4);
          asm volatile("ds_read_b64_tr_b16 %0, %1" : "=v"(vlo[db]) : "v"(a1));
          asm volatile("ds_read_b64_tr_b16 %0, %1" : "=v"(vhi[db]) : "v"(a2));
        }
        asm volatile("s_waitcnt lgkmcnt(0)" ::: "memory");
        __builtin_amdgcn_sched_barrier(0);
#pragma unroll
        for (int db = 0; db < 8; ++db) {
          const f16x8 vf = __builtin_shufflevector(vlo[db], vhi[db],
                                                   0, 1, 2, 3, 4, 5, 6, 7);
#pragma unroll
          for (int rb = 0; rb < 2; ++rb)
            if (act[rb])
              oacc[rb][db] = mfma16x32(pa[rb], vf, oacc[rb][db]);
        }
      }
    }
    __syncthreads();
  }
  // ---- epilogue: O / l ----
#pragma unroll
  for (int rb = 0; rb < 2; ++rb)
#pragma unroll
    for (int db = 0; db < 8; ++db)
#pragma unroll
      for (int r = 0; r < 4; ++r) {
        const int row = tb + qrow[rb] + g * 4 + r;
        const int col = h * 128 + db * 16 + li;
        O[(size_t)row * 2048 + col] = (_Float16)(oacc[rb][db][r] / l_r[rb][r]);
      }
}

// ---------------------------------------------------------------------------
extern "C" void kernel_launch(void* const* d_in, const int* in_sizes, int n_in,
                              void* d_out, int out_size, void* d_ws, size_t ws_size,
                              hipStream_t stream) {
  const float* x         = (const float*)d_in[0];
  const int*   positions = (const int*)d_in[1];
  const float* wqkv      = (const float*)d_in[2];
  const float* wo        = (const float*)d_in[3];
  float* out = (float*)d_out;

  char* ws = (char*)d_ws;
  _Float16* qkv    = (_Float16*)(ws);                    // 100663296 B
  _Float16* xf     = (_Float16*)(ws + 100663296);        //  33554432 B
  _Float16* wqkvf  = (_Float16*)(ws + 134217728);        //  25165824 B
  _Float16* wof    = (_Float16*)(ws + 159383552);        //   8388608 B
  _Float16* of     = xf;  // reuse x region for attention output

  cvt3_f32_f16<<<32768, 256, 0, stream>>>(x, xf, wqkv, wqkvf, wo, wof);

  gemm_bt5<_Float16><<<768, 512, 0, stream>>>(xf, wqkvf, qkv, 8192, 6144, 2048);

  attn_kernel<<<512, 512, 0, stream>>>(qkv, of, positions);

  gemm_bt5<float><<<256, 512, 0, stream>>>(of, wof, out, 8192, 2048, 2048);
}

// Round 12
// 342.933 us; speedup vs baseline: 1.0090x; 1.0090x over previous
//
#include <hip/hip_runtime.h>
#include <cstddef>

// ---------------------------------------------------------------------------
// Fused attention block for MI355X (gfx950), FP16 MFMA pipeline.
// B=32, S=256, DIM=2048, NH=16, NKV=16, HD=128, GRID=16, BASE=10000, CLS=1.
//
// Pipeline:
//   1. cvt3: x, wqkv, wo  f32 -> f16 (single kernel)
//   2. gemm_bt5: qkv = x @ wqkv^T          (8192x6144x2048, f16 out)
//   3. attn: causal flash attention, FUSED 2D-RoPE on Q (regs) and K
//      (staging), software-pipelined staging: V double-buffered via async
//      gload16 issued before compute; K global->reg loads issued before
//      compute, rope+ds_write after a raw (non-draining) barrier.
//      V consumed through ds_read_b64_tr_b16 (HW transpose).
//   4. gemm_bt5: out = O @ wo^T            (8192x2048x2048, f32 out)
//
// gemm_bt5 (R10 measured: ~187us, MfmaUtil 50%): 256x256 tile, BK=64,
// 8 waves (2m x 4n), 2-deep LDS double buffer, row-split half-tiles;
// per phase: {ds_reads; stage 1 half-tile; setprio(1); MFMA x16;
// setprio(0); [vmcnt(6) at p1,p3 only]; BAR}.
// ---------------------------------------------------------------------------

typedef float    f32x4 __attribute__((ext_vector_type(4)));
typedef _Float16 f16x8 __attribute__((ext_vector_type(8)));
typedef _Float16 f16x4 __attribute__((ext_vector_type(4)));

#define LOG2E 1.4426950408889634f
#define NLOG2B_32 (-0.41524101186192697f)   // -log2(10000)/32

__device__ static inline f32x4 mfma16x32(f16x8 a, f16x8 b, f32x4 c) {
  return __builtin_amdgcn_mfma_f32_16x16x32_f16(a, b, c, 0, 0, 0);
}

// async global->LDS, 16B per lane; lds must be the wave-uniform base
// (HW dest = base + lane*16).
__device__ static inline void gload16(const void* g, void* lds) {
  __builtin_amdgcn_global_load_lds(
      (const __attribute__((address_space(1))) unsigned int*)g,
      (__attribute__((address_space(3))) unsigned int*)lds, 16, 0, 0);
}

#define BAR()    asm volatile("s_barrier" ::: "memory")
#define VMCNT6() asm volatile("s_waitcnt vmcnt(6)" ::: "memory")

// ---------------- 1. f32 -> f16 convert (three buffers, one kernel) --------
__global__ void cvt3_f32_f16(const float* __restrict__ s0, _Float16* __restrict__ d0,
                             const float* __restrict__ s1, _Float16* __restrict__ d1,
                             const float* __restrict__ s2, _Float16* __restrict__ d2) {
  int i = blockIdx.x * blockDim.x + threadIdx.x;   // quad index
  const float* src; _Float16* dst;
  if (i < 4194304)      { src = s0; dst = d0; }
  else if (i < 7340032) { src = s1; dst = d1; i -= 4194304; }
  else                  { src = s2; dst = d2; i -= 7340032; }
  f32x4 v = *(const f32x4*)(src + (size_t)i * 4);
  f16x4 o;
  o[0] = (_Float16)v[0]; o[1] = (_Float16)v[1];
  o[2] = (_Float16)v[2]; o[3] = (_Float16)v[3];
  *(f16x4*)(dst + (size_t)i * 4) = o;
}

// ---------------- 2./4. GEMM: C[m,n] = sum_k A[m,k] * Bt[n,k] ----------------
// 256x256 tile, BK=64, 8 waves (2m x 4n), 2-deep LDS double buffer.
// Per K-tile 4 phases, one C-quadrant (16 MFMA) each:
//   p0: read af0(8) bf0(4); stage B0(T+1)->nb; MFMA af0 x bf0
//   p1: read bf1(4);        stage B1(T+1)->nb; MFMA af0 x bf1; vmcnt(6)
//   p2: read af1(8);        stage A1(T+1)->nb; MFMA af1 x bf0
//   p3:                     stage A0(T+2)->cb; MFMA af1 x bf1; vmcnt(6)
// One barrier per phase; vmcnt gates at p1/p3 only (m201 cadence).
template <typename OutT>
__global__ void __launch_bounds__(512, 2)
gemm_bt5(const _Float16* __restrict__ A, const _Float16* __restrict__ Bt,
         OutT* __restrict__ C, int M, int N, int K) {
  __shared__ __attribute__((aligned(16))) _Float16 Ab[2][256 * 64];
  __shared__ __attribute__((aligned(16))) _Float16 Bb[2][256 * 64];

  const int tid  = threadIdx.x;
  const int lane = tid & 63;
  const int w    = tid >> 6;
  const int wm   = w >> 2, wn = w & 3;
  const int g    = lane >> 4, li = lane & 15;

  // T1: XCD-aware block swizzle (grid multiple of 8 for our shapes)
  const int nwg = (int)gridDim.x;
  const int cpx = nwg >> 3;
  const int bid = (int)blockIdx.x;
  const int swz = (bid & 7) * cpx + (bid >> 3);
  const int nbn = N >> 8;
  const int bm  = (swz / nbn) << 8;
  const int bn  = (swz % nbn) << 8;
  const int NT  = K >> 6;

  // ---- staging: half-tile = 128 rows x 64 cols = 1024 chunks of 16B.
  // Thread t, load j covers linear chunk L = j*512 + t  (row L>>3, phys L&7),
  // holding logical chunk (L&7)^((L>>3)&7) -> global col ((t&7)^((t>>3)&7))*8.
  const int srow = tid >> 3;                       // 0..63
  const int scol = ((tid & 7) ^ (srow & 7)) * 8;   // pre-swizzled col (elems)
  const _Float16* gA = A  + (size_t)(bm + srow) * K + scol;
  const _Float16* gB = Bt + (size_t)(bn + srow) * K + scol;
  const int sdst = w * 1024;                       // wave-uniform byte base

  auto stage = [&](const _Float16* gbase, _Float16* lbase, int h, int kt) {
    const _Float16* gp = gbase + (size_t)h * 128 * K + kt;
    char* lp = (char*)lbase + h * 16384;
#pragma unroll
    for (int j = 0; j < 2; ++j)
      gload16(gp + (size_t)j * 64 * K, lp + j * 8192 + sdst);
  };

  // frag read: logical chunk (k2*4+g) of row -> phys chunk ^(row&7)=^(li&7)
  auto rdfrag = [&](const _Float16* buf, int row, int k2) -> f16x8 {
    const int pc = ((k2 << 2) + g) ^ (li & 7);
    return *(const f16x8*)((const char*)buf + row * 128 + pc * 16);
  };

  f32x4 acc[8][4] = {};

  // ---- prologue: A0(0) B0(0) B1(0) A1(0) A0(1); wait all but newest 3 ----
  stage(gA, Ab[0], 0, 0);
  stage(gB, Bb[0], 0, 0);
  stage(gB, Bb[0], 1, 0);
  stage(gA, Ab[0], 1, 0);
  stage(gA, Ab[1], 0, (NT > 1) ? 64 : 0);
  VMCNT6();
  BAR();

  for (int T = 0; T < NT; ++T) {
    const int cb = T & 1, nb = cb ^ 1;
    const _Float16* Ac = Ab[cb];
    const _Float16* Bc = Bb[cb];
    const int ktN  = (T + 1 < NT) ? (T + 1) << 6 : 0;
    const int ktN2 = (T + 2 < NT) ? (T + 2) << 6 : 0;

    f16x8 af0[4][2], af1[4][2], bf0[2][2], bf1[2][2];

    // ---- p0: read af0+bf0; stage B0(T+1); MFMA (m0-3 x n0-1) ----
#pragma unroll
    for (int m = 0; m < 4; ++m)
#pragma unroll
      for (int k2 = 0; k2 < 2; ++k2)
        af0[m][k2] = rdfrag(Ac, wm * 128 + m * 16 + li, k2);
#pragma unroll
    for (int n = 0; n < 2; ++n)
#pragma unroll
      for (int k2 = 0; k2 < 2; ++k2)
        bf0[n][k2] = rdfrag(Bc, wn * 64 + n * 16 + li, k2);
    stage(gB, Bb[nb], 0, ktN);
    __builtin_amdgcn_s_setprio(1);
#pragma unroll
    for (int m = 0; m < 4; ++m)
#pragma unroll
      for (int n = 0; n < 2; ++n)
#pragma unroll
        for (int k2 = 0; k2 < 2; ++k2)
          acc[m][n] = mfma16x32(af0[m][k2], bf0[n][k2], acc[m][n]);
    __builtin_amdgcn_s_setprio(0);
    BAR();

    // ---- p1: read bf1; stage B1(T+1); MFMA (m0-3 x n2-3); vmcnt gate ----
#pragma unroll
    for (int n = 0; n < 2; ++n)
#pragma unroll
      for (int k2 = 0; k2 < 2; ++k2)
        bf1[n][k2] = rdfrag(Bc, wn * 64 + (n + 2) * 16 + li, k2);
    stage(gB, Bb[nb], 1, ktN);
    __builtin_amdgcn_s_setprio(1);
#pragma unroll
    for (int m = 0; m < 4; ++m)
#pragma unroll
      for (int n = 0; n < 2; ++n)
#pragma unroll
        for (int k2 = 0; k2 < 2; ++k2)
          acc[m][n + 2] = mfma16x32(af0[m][k2], bf1[n][k2], acc[m][n + 2]);
    __builtin_amdgcn_s_setprio(0);
    VMCNT6();
    BAR();

    // ---- p2: read af1; stage A1(T+1); MFMA (m4-7 x n0-1) ----
#pragma unroll
    for (int m = 0; m < 4; ++m)
#pragma unroll
      for (int k2 = 0; k2 < 2; ++k2)
        af1[m][k2] = rdfrag(Ac, wm * 128 + (m + 4) * 16 + li, k2);
    stage(gA, Ab[nb], 1, ktN);
    __builtin_amdgcn_s_setprio(1);
#pragma unroll
    for (int m = 0; m < 4; ++m)
#pragma unroll
      for (int n = 0; n < 2; ++n)
#pragma unroll
        for (int k2 = 0; k2 < 2; ++k2)
          acc[m + 4][n] = mfma16x32(af1[m][k2], bf0[n][k2], acc[m + 4][n]);
    __builtin_amdgcn_s_setprio(0);
    BAR();

    // ---- p3: stage A0(T+2)->cb (A0 last read at p2, one BAR ago); MFMA ----
    stage(gA, Ab[cb], 0, ktN2);
    __builtin_amdgcn_s_setprio(1);
#pragma unroll
    for (int m = 0; m < 4; ++m)
#pragma unroll
      for (int n = 0; n < 2; ++n)
#pragma unroll
        for (int k2 = 0; k2 < 2; ++k2)
          acc[m + 4][n + 2] = mfma16x32(af1[m][k2], bf1[n][k2], acc[m + 4][n + 2]);
    __builtin_amdgcn_s_setprio(0);
    VMCNT6();
    BAR();
  }

  asm volatile("s_waitcnt vmcnt(0)" ::: "memory");  // drain tail garbage loads

  // ---- epilogue: D row = g*4+r, col = li (m89-verified layout) ----
#pragma unroll
  for (int m = 0; m < 8; ++m)
#pragma unroll
    for (int n = 0; n < 4; ++n)
#pragma unroll
      for (int r = 0; r < 4; ++r) {
        const int row = bm + wm * 128 + m * 16 + g * 4 + r;
        const int col = bn + wn * 64 + n * 16 + li;
        C[(size_t)row * N + col] = (OutT)acc[m][n][r];
      }
}

// ---------------- 3. causal flash attention + fused 2D RoPE, pipelined -----
// 1 block = 1 (b,h), 512 threads = 8 waves. Wave w owns q-row blocks
// (w, 15-w): balanced causal work.
// Staging pipeline per k-tile kt: {issue V(kt+1) gload -> Vt[kt+1 & 1];
// load K(kt+1) -> regs; COMPUTE(kt); raw s_barrier (no vmcnt drain!);
// rope+ds_write K(kt+1) -> Ks; vmcnt(0)+lgkmcnt(0); s_barrier}.
// BAR_a needs no drain: each wave's Ks ds_reads are consumed by its own
// MFMAs before it arrives; V(kt+1) loads stay in flight across it.
//   Ks: row-major [64][128], 16B chunk c at phys c^(key&7) (conflict-free).
//   Vt: 2 x row-major [64 key][128 d], same chunk swizzle, async gload16;
//       PV B-frags via ds_read_b64_tr_b16 (m156 model, R9-verified).
//   Ps: per-wave P round-trip (D-frag -> A-frag layout), stride 40.
__global__ void __launch_bounds__(512)
attn_kernel(const _Float16* __restrict__ qkv, _Float16* __restrict__ O,
            const int* __restrict__ positions) {
  const int b  = blockIdx.x >> 4;
  const int h  = blockIdx.x & 15;
  const int tb = b << 8;
  const int tid = threadIdx.x;
  const int lane = tid & 63;
  const int w = tid >> 6;
  const int g = lane >> 4, li = lane & 15;

  __shared__ __attribute__((aligned(16))) _Float16 Ks[64 * 128];
  __shared__ __attribute__((aligned(16))) _Float16 Vt[2][64 * 128];
  __shared__ __attribute__((aligned(16))) _Float16 Ps[8][32 * 40];
  __shared__ float2 tab[512];
  __shared__ int    ptab[256];

  // ---- staging helpers ----
  auto issueV = [&](int kt, int vb) {
#pragma unroll
    for (int i = 0; i < 2; ++i) {
      const int s = i * 512 + tid;
      const int key = s >> 4;
      const int sch = (s & 15) ^ (key & 7);
      gload16(qkv + (size_t)(tb + kt * 64 + key) * 6144 + 4096 + h * 128 + sch * 8,
              (char*)Vt[vb] + (i * 512 + (tid & ~63)) * 16);
    }
  };

  f16x8 kreg[2];
  auto loadK = [&](int kt) {
#pragma unroll
    for (int i = 0; i < 2; ++i) {
      const int s = i * 512 + tid;
      const int key = s >> 4;
      const int c = s & 15;
      kreg[i] = *(const f16x8*)(qkv + (size_t)(tb + kt * 64 + key) * 6144
                                + 2048 + h * 128 + c * 8);
    }
  };
  auto ropeWriteK = [&](int kt) {
#pragma unroll
    for (int i = 0; i < 2; ++i) {
      const int s = i * 512 + tid;
      const int key = s >> 4;
      const int c = s & 15;   // logical 16B chunk (4 rope pairs)
      const int pos = ptab[kt * 64 + key];
      const f16x8 v = kreg[i];
      f16x8 o;
      if (pos == 0) {
#pragma unroll
        for (int u = 0; u < 8; ++u) o[u] = (_Float16)0.f;
      } else {
        const int iv = (pos - 1) >> 4, jv = (pos - 1) & 15;
        const int tv = (c < 8) ? iv : jv;    // d2 = c*4+u < 32 <=> c<8
#pragma unroll
        for (int u = 0; u < 4; ++u) {
          const float2 cs = tab[tv * 32 + ((c * 4 + u) & 31)];
          const float x0 = (float)v[2 * u], x1 = (float)v[2 * u + 1];
          o[2 * u]     = (_Float16)(x0 * cs.x - x1 * cs.y);
          o[2 * u + 1] = (_Float16)(x1 * cs.x + x0 * cs.y);
        }
      }
      *(f16x8*)((char*)Ks + key * 256 + (c ^ (key & 7)) * 16) = o;
    }
  };

  // ---- prologue: V(0) in flight under table build + Q rope ----
  issueV(0, 0);
  {
    const float ang = (float)(tid >> 5) * exp2f((float)(tid & 31) * NLOG2B_32);
    float s, c;
    sincosf(ang, &s, &c);
    tab[tid] = make_float2(c, s);
    if (tid < 256) ptab[tid] = positions[tb + tid];
  }
  asm volatile("s_waitcnt lgkmcnt(0)" ::: "memory");
  BAR();   // tab/ptab visible; V(0) gloads still in flight

  const int qb[2]   = {w, 15 - w};
  const int qrow[2] = {qb[0] * 16, qb[1] * 16};
  const int kmax[2] = {qb[0] >> 2, qb[1] >> 2};

  // tr-read per-lane constants: li = jj*4 + cc
  const int jj = li >> 2;
  const int cc = li & 3;
  const unsigned vbase =
      (unsigned)(unsigned long long)(__attribute__((address_space(3))) _Float16*)Vt;

  // ---- load Q + rope in registers ----
  f16x8 qf[2][4];
#pragma unroll
  for (int rb = 0; rb < 2; ++rb) {
    const int pos = ptab[qrow[rb] + li];
    const int iv = (pos - 1) >> 4, jv = (pos - 1) & 15;
#pragma unroll
    for (int ks = 0; ks < 4; ++ks) {
      f16x8 v = *(const f16x8*)(qkv + (size_t)(tb + qrow[rb] + li) * 6144
                                + h * 128 + ks * 32 + g * 8);
      f16x8 o;
      if (pos == 0) {
#pragma unroll
        for (int u = 0; u < 8; ++u) o[u] = (_Float16)0.f;
      } else {
        const int tv = (ks < 2) ? iv : jv;   // d2 = ks*16+g*4+u < 32 <=> ks<2
#pragma unroll
        for (int u = 0; u < 4; ++u) {
          const float2 cs = tab[tv * 32 + ((ks * 16 + g * 4 + u) & 31)];
          const float x0 = (float)v[2 * u], x1 = (float)v[2 * u + 1];
          o[2 * u]     = (_Float16)(x0 * cs.x - x1 * cs.y);
          o[2 * u + 1] = (_Float16)(x1 * cs.x + x0 * cs.y);
        }
      }
      qf[rb][ks] = o;
    }
  }

  loadK(0);
  ropeWriteK(0);
  asm volatile("s_waitcnt vmcnt(0) lgkmcnt(0)" ::: "memory");
  BAR();   // Ks(0) + Vt[0] ready

  f32x4 oacc[2][8] = {};
  float m_r[2][4], l_r[2][4];
#pragma unroll
  for (int rb = 0; rb < 2; ++rb)
#pragma unroll
    for (int r = 0; r < 4; ++r) { m_r[rb][r] = -1e30f; l_r[rb][r] = 0.f; }

  const float scale = 0.08838834764831845f;  // 1/sqrt(128)

  for (int kt = 0; kt < 4; ++kt) {
    const int vb = kt & 1;
    if (kt < 3) {                  // pipeline: next tile's loads in flight
      issueV(kt + 1, vb ^ 1);
      loadK(kt + 1);
    }

    const bool act[2] = {kt <= kmax[0], kt <= kmax[1]};
    if (act[0] || act[1]) {
      // ---- S = Q K^T (64 keys) ----
      f32x4 sacc[2][4] = {};
#pragma unroll
      for (int ks = 0; ks < 4; ++ks) {
        f16x8 kf[4];
#pragma unroll
        for (int cb = 0; cb < 4; ++cb) {
          const int key = cb * 16 + li;
          const int chunk = (ks * 4 + g) ^ (key & 7);
          kf[cb] = *(const f16x8*)((const char*)Ks + key * 256 + chunk * 16);
        }
#pragma unroll
        for (int rb = 0; rb < 2; ++rb)
          if (act[rb])
#pragma unroll
            for (int cb = 0; cb < 4; ++cb)
              sacc[rb][cb] = mfma16x32(qf[rb][ks], kf[cb], sacc[rb][cb]);
      }
      // ---- online softmax (wave-parallel, 16-lane-group shfl reduce) ----
#pragma unroll
      for (int rb = 0; rb < 2; ++rb) {
        if (!act[rb]) continue;
#pragma unroll
        for (int r = 0; r < 4; ++r) {
          const int q = qrow[rb] + g * 4 + r;
          float mx = -1e30f;
#pragma unroll
          for (int cb = 0; cb < 4; ++cb) {
            float sv = sacc[rb][cb][r] * scale;
            const int key = kt * 64 + cb * 16 + li;
            sv = (key <= q) ? sv : -1e30f;
            sacc[rb][cb][r] = sv;
            mx = fmaxf(mx, sv);
          }
#pragma unroll
          for (int off = 1; off < 16; off <<= 1)
            mx = fmaxf(mx, __shfl_xor(mx, off));
          const float mold = m_r[rb][r];
          const float mnew = fmaxf(mold, mx);
          const float alpha = exp2f((mold - mnew) * LOG2E);
          float rsum = 0.f;
#pragma unroll
          for (int cb = 0; cb < 4; ++cb) {
            const float pv = exp2f((sacc[rb][cb][r] - mnew) * LOG2E);
            sacc[rb][cb][r] = pv;
            rsum += pv;
          }
#pragma unroll
          for (int off = 1; off < 16; off <<= 1)
            rsum += __shfl_xor(rsum, off);
          m_r[rb][r] = mnew;
          l_r[rb][r] = l_r[rb][r] * alpha + rsum;
#pragma unroll
          for (int db = 0; db < 8; ++db)
            oacc[rb][db][r] *= alpha;
        }
      }
      // ---- O += P V, two 32-key halves; V frags via ds_read_b64_tr_b16 ----
#pragma unroll
      for (int ks2 = 0; ks2 < 2; ++ks2) {
#pragma unroll
        for (int rb = 0; rb < 2; ++rb) {
          if (!act[rb]) continue;
#pragma unroll
          for (int cbh = 0; cbh < 2; ++cbh) {
            const int cb = ks2 * 2 + cbh;
#pragma unroll
            for (int r = 0; r < 4; ++r)
              Ps[w][(rb * 16 + g * 4 + r) * 40 + cbh * 16 + li] =
                  (_Float16)sacc[rb][cb][r];
          }
        }
        asm volatile("s_waitcnt lgkmcnt(0)" ::: "memory");
        f16x8 pa[2];
#pragma unroll
        for (int rb = 0; rb < 2; ++rb)
          if (act[rb])
            pa[rb] = *(const f16x8*)(&Ps[w][(rb * 16 + li) * 40 + g * 8]);

        // V B-frags: rows ks2*32+g*8+jj (+4), d-window db*16, swizzled chunks
        f16x4 vlo[8], vhi[8];
        const int rowA = ks2 * 32 + g * 8 + jj;
        const unsigned base1 = vbase + (unsigned)(vb * 16384)
                             + (unsigned)(rowA * 256 + (cc & 1) * 8);
        const unsigned base2 = base1 + 4 * 256;
#pragma unroll
        for (int db = 0; db < 8; ++db) {
          const int ch = db * 2 + (cc >> 1);
          const unsigned a1 = base1 + (unsigned)((ch ^ jj) << 4);
          const unsigned a2 = base2 + (unsigned)((ch ^ jj ^ 4) << 4);
          asm volatile("ds_read_b64_tr_b16 %0, %1" : "=v"(vlo[db]) : "v"(a1));
          asm volatile("ds_read_b64_tr_b16 %0, %1" : "=v"(vhi[db]) : "v"(a2));
        }
        asm volatile("s_waitcnt lgkmcnt(0)" ::: "memory");
        __builtin_amdgcn_sched_barrier(0);
#pragma unroll
        for (int db = 0; db < 8; ++db) {
          const f16x8 vf = __builtin_shufflevector(vlo[db], vhi[db],
                                                   0, 1, 2, 3, 4, 5, 6, 7);
#pragma unroll
          for (int rb = 0; rb < 2; ++rb)
            if (act[rb])
              oacc[rb][db] = mfma16x32(pa[rb], vf, oacc[rb][db]);
        }
      }
    }

    // BAR_a: all waves done reading Ks(kt); own ds reads already consumed,
    // V(kt+1) gloads stay in flight (no vmcnt drain on raw s_barrier).
    BAR();
    if (kt < 3) ropeWriteK(kt + 1);
    asm volatile("s_waitcnt vmcnt(0) lgkmcnt(0)" ::: "memory");
    BAR();   // Ks(kt+1) visible + V(kt+1) landed
  }

  // ---- epilogue: O / l ----
#pragma unroll
  for (int rb = 0; rb < 2; ++rb)
#pragma unroll
    for (int db = 0; db < 8; ++db)
#pragma unroll
      for (int r = 0; r < 4; ++r) {
        const int row = tb + qrow[rb] + g * 4 + r;
        const int col = h * 128 + db * 16 + li;
        O[(size_t)row * 2048 + col] = (_Float16)(oacc[rb][db][r] / l_r[rb][r]);
      }
}

// ---------------------------------------------------------------------------
extern "C" void kernel_launch(void* const* d_in, const int* in_sizes, int n_in,
                              void* d_out, int out_size, void* d_ws, size_t ws_size,
                              hipStream_t stream) {
  const float* x         = (const float*)d_in[0];
  const int*   positions = (const int*)d_in[1];
  const float* wqkv      = (const float*)d_in[2];
  const float* wo        = (const float*)d_in[3];
  float* out = (float*)d_out;

  char* ws = (char*)d_ws;
  _Float16* qkv    = (_Float16*)(ws);                    // 100663296 B
  _Float16* xf     = (_Float16*)(ws + 100663296);        //  33554432 B
  _Float16* wqkvf  = (_Float16*)(ws + 134217728);        //  25165824 B
  _Float16* wof    = (_Float16*)(ws + 159383552);        //   8388608 B
  _Float16* of     = xf;  // reuse x region for attention output

  cvt3_f32_f16<<<32768, 256, 0, stream>>>(x, xf, wqkv, wqkvf, wo, wof);

  gemm_bt5<_Float16><<<768, 512, 0, stream>>>(xf, wqkvf, qkv, 8192, 6144, 2048);

  attn_kernel<<<512, 512, 0, stream>>>(qkv, of, positions);

  gemm_bt5<float><<<256, 512, 0, stream>>>(of, wof, out, 8192, 2048, 2048);
}

// Round 13
// 337.029 us; speedup vs baseline: 1.0266x; 1.0175x over previous
//
#include <hip/hip_runtime.h>
#include <cstddef>

// ---------------------------------------------------------------------------
// Fused attention block for MI355X (gfx950), FP16 MFMA pipeline.
// B=32, S=256, DIM=2048, NH=16, NKV=16, HD=128, GRID=16, BASE=10000, CLS=1.
//
// Pipeline:
//   1. cvt3: x, wqkv, wo  f32 -> f16 (single kernel)
//   2. gemm_bt5: qkv = x @ wqkv^T          (8192x6144x2048, f16 out)
//   3. attn: causal flash attention, FUSED 2D-RoPE on Q (regs, scale folded)
//      and K (staging); pipelined staging (V dbuf async gload16, K to regs
//      early); DPP row_ror softmax reduces; skip-identity rescale;
//      V consumed through ds_read_b64_tr_b16.
//   4. gemm_bt5: out = O @ wo^T            (8192x2048x2048, f32 out)
//
// gemm_bt5 (R10 measured: ~187us, MfmaUtil 50%): 256x256 tile, BK=64,
// 8 waves (2m x 4n), 2-deep LDS double buffer, row-split half-tiles;
// per phase: {ds_reads; stage 1 half-tile; setprio(1); MFMA x16;
// setprio(0); [vmcnt(6) at p1,p3 only]; BAR}.
// ---------------------------------------------------------------------------

typedef float    f32x4 __attribute__((ext_vector_type(4)));
typedef _Float16 f16x8 __attribute__((ext_vector_type(8)));
typedef _Float16 f16x4 __attribute__((ext_vector_type(4)));

#define LOG2E 1.4426950408889634f
#define NLOG2B_32 (-0.41524101186192697f)   // -log2(10000)/32

__device__ static inline f32x4 mfma16x32(f16x8 a, f16x8 b, f32x4 c) {
  return __builtin_amdgcn_mfma_f32_16x16x32_f16(a, b, c, 0, 0, 0);
}

// async global->LDS, 16B per lane; lds must be the wave-uniform base
// (HW dest = base + lane*16).
__device__ static inline void gload16(const void* g, void* lds) {
  __builtin_amdgcn_global_load_lds(
      (const __attribute__((address_space(1))) unsigned int*)g,
      (__attribute__((address_space(3))) unsigned int*)lds, 16, 0, 0);
}

// DPP row_ror<N> (rotation within 16-lane row) — VALU-only cross-lane.
template <int CTRL>
__device__ static inline float dppror(float x) {
  return __builtin_bit_cast(float, __builtin_amdgcn_update_dpp(
      __builtin_bit_cast(int, x), __builtin_bit_cast(int, x),
      CTRL, 0xf, 0xf, false));
}

#define BAR()    asm volatile("s_barrier" ::: "memory")
#define VMCNT6() asm volatile("s_waitcnt vmcnt(6)" ::: "memory")

// ---------------- 1. f32 -> f16 convert (three buffers, one kernel) --------
__global__ void cvt3_f32_f16(const float* __restrict__ s0, _Float16* __restrict__ d0,
                             const float* __restrict__ s1, _Float16* __restrict__ d1,
                             const float* __restrict__ s2, _Float16* __restrict__ d2) {
  int i = blockIdx.x * blockDim.x + threadIdx.x;   // quad index
  const float* src; _Float16* dst;
  if (i < 4194304)      { src = s0; dst = d0; }
  else if (i < 7340032) { src = s1; dst = d1; i -= 4194304; }
  else                  { src = s2; dst = d2; i -= 7340032; }
  f32x4 v = *(const f32x4*)(src + (size_t)i * 4);
  f16x4 o;
  o[0] = (_Float16)v[0]; o[1] = (_Float16)v[1];
  o[2] = (_Float16)v[2]; o[3] = (_Float16)v[3];
  *(f16x4*)(dst + (size_t)i * 4) = o;
}

// ---------------- 2./4. GEMM: C[m,n] = sum_k A[m,k] * Bt[n,k] ----------------
// 256x256 tile, BK=64, 8 waves (2m x 4n), 2-deep LDS double buffer.
// Per K-tile 4 phases, one C-quadrant (16 MFMA) each:
//   p0: read af0(8) bf0(4); stage B0(T+1)->nb; MFMA af0 x bf0
//   p1: read bf1(4);        stage B1(T+1)->nb; MFMA af0 x bf1; vmcnt(6)
//   p2: read af1(8);        stage A1(T+1)->nb; MFMA af1 x bf0
//   p3:                     stage A0(T+2)->cb; MFMA af1 x bf1; vmcnt(6)
// One barrier per phase; vmcnt gates at p1/p3 only (m201 cadence).
template <typename OutT>
__global__ void __launch_bounds__(512, 2)
gemm_bt5(const _Float16* __restrict__ A, const _Float16* __restrict__ Bt,
         OutT* __restrict__ C, int M, int N, int K) {
  __shared__ __attribute__((aligned(16))) _Float16 Ab[2][256 * 64];
  __shared__ __attribute__((aligned(16))) _Float16 Bb[2][256 * 64];

  const int tid  = threadIdx.x;
  const int lane = tid & 63;
  const int w    = tid >> 6;
  const int wm   = w >> 2, wn = w & 3;
  const int g    = lane >> 4, li = lane & 15;

  // T1: XCD-aware block swizzle (grid multiple of 8 for our shapes)
  const int nwg = (int)gridDim.x;
  const int cpx = nwg >> 3;
  const int bid = (int)blockIdx.x;
  const int swz = (bid & 7) * cpx + (bid >> 3);
  const int nbn = N >> 8;
  const int bm  = (swz / nbn) << 8;
  const int bn  = (swz % nbn) << 8;
  const int NT  = K >> 6;

  // ---- staging: half-tile = 128 rows x 64 cols = 1024 chunks of 16B.
  // Thread t, load j covers linear chunk L = j*512 + t  (row L>>3, phys L&7),
  // holding logical chunk (L&7)^((L>>3)&7) -> global col ((t&7)^((t>>3)&7))*8.
  const int srow = tid >> 3;                       // 0..63
  const int scol = ((tid & 7) ^ (srow & 7)) * 8;   // pre-swizzled col (elems)
  const _Float16* gA = A  + (size_t)(bm + srow) * K + scol;
  const _Float16* gB = Bt + (size_t)(bn + srow) * K + scol;
  const int sdst = w * 1024;                       // wave-uniform byte base

  auto stage = [&](const _Float16* gbase, _Float16* lbase, int h, int kt) {
    const _Float16* gp = gbase + (size_t)h * 128 * K + kt;
    char* lp = (char*)lbase + h * 16384;
#pragma unroll
    for (int j = 0; j < 2; ++j)
      gload16(gp + (size_t)j * 64 * K, lp + j * 8192 + sdst);
  };

  // frag read: logical chunk (k2*4+g) of row -> phys chunk ^(row&7)=^(li&7)
  auto rdfrag = [&](const _Float16* buf, int row, int k2) -> f16x8 {
    const int pc = ((k2 << 2) + g) ^ (li & 7);
    return *(const f16x8*)((const char*)buf + row * 128 + pc * 16);
  };

  f32x4 acc[8][4] = {};

  // ---- prologue: A0(0) B0(0) B1(0) A1(0) A0(1); wait all but newest 3 ----
  stage(gA, Ab[0], 0, 0);
  stage(gB, Bb[0], 0, 0);
  stage(gB, Bb[0], 1, 0);
  stage(gA, Ab[0], 1, 0);
  stage(gA, Ab[1], 0, (NT > 1) ? 64 : 0);
  VMCNT6();
  BAR();

  for (int T = 0; T < NT; ++T) {
    const int cb = T & 1, nb = cb ^ 1;
    const _Float16* Ac = Ab[cb];
    const _Float16* Bc = Bb[cb];
    const int ktN  = (T + 1 < NT) ? (T + 1) << 6 : 0;
    const int ktN2 = (T + 2 < NT) ? (T + 2) << 6 : 0;

    f16x8 af0[4][2], af1[4][2], bf0[2][2], bf1[2][2];

    // ---- p0: read af0+bf0; stage B0(T+1); MFMA (m0-3 x n0-1) ----
#pragma unroll
    for (int m = 0; m < 4; ++m)
#pragma unroll
      for (int k2 = 0; k2 < 2; ++k2)
        af0[m][k2] = rdfrag(Ac, wm * 128 + m * 16 + li, k2);
#pragma unroll
    for (int n = 0; n < 2; ++n)
#pragma unroll
      for (int k2 = 0; k2 < 2; ++k2)
        bf0[n][k2] = rdfrag(Bc, wn * 64 + n * 16 + li, k2);
    stage(gB, Bb[nb], 0, ktN);
    __builtin_amdgcn_s_setprio(1);
#pragma unroll
    for (int m = 0; m < 4; ++m)
#pragma unroll
      for (int n = 0; n < 2; ++n)
#pragma unroll
        for (int k2 = 0; k2 < 2; ++k2)
          acc[m][n] = mfma16x32(af0[m][k2], bf0[n][k2], acc[m][n]);
    __builtin_amdgcn_s_setprio(0);
    BAR();

    // ---- p1: read bf1; stage B1(T+1); MFMA (m0-3 x n2-3); vmcnt gate ----
#pragma unroll
    for (int n = 0; n < 2; ++n)
#pragma unroll
      for (int k2 = 0; k2 < 2; ++k2)
        bf1[n][k2] = rdfrag(Bc, wn * 64 + (n + 2) * 16 + li, k2);
    stage(gB, Bb[nb], 1, ktN);
    __builtin_amdgcn_s_setprio(1);
#pragma unroll
    for (int m = 0; m < 4; ++m)
#pragma unroll
      for (int n = 0; n < 2; ++n)
#pragma unroll
        for (int k2 = 0; k2 < 2; ++k2)
          acc[m][n + 2] = mfma16x32(af0[m][k2], bf1[n][k2], acc[m][n + 2]);
    __builtin_amdgcn_s_setprio(0);
    VMCNT6();
    BAR();

    // ---- p2: read af1; stage A1(T+1); MFMA (m4-7 x n0-1) ----
#pragma unroll
    for (int m = 0; m < 4; ++m)
#pragma unroll
      for (int k2 = 0; k2 < 2; ++k2)
        af1[m][k2] = rdfrag(Ac, wm * 128 + (m + 4) * 16 + li, k2);
    stage(gA, Ab[nb], 1, ktN);
    __builtin_amdgcn_s_setprio(1);
#pragma unroll
    for (int m = 0; m < 4; ++m)
#pragma unroll
      for (int n = 0; n < 2; ++n)
#pragma unroll
        for (int k2 = 0; k2 < 2; ++k2)
          acc[m + 4][n] = mfma16x32(af1[m][k2], bf0[n][k2], acc[m + 4][n]);
    __builtin_amdgcn_s_setprio(0);
    BAR();

    // ---- p3: stage A0(T+2)->cb (A0 last read at p2, one BAR ago); MFMA ----
    stage(gA, Ab[cb], 0, ktN2);
    __builtin_amdgcn_s_setprio(1);
#pragma unroll
    for (int m = 0; m < 4; ++m)
#pragma unroll
      for (int n = 0; n < 2; ++n)
#pragma unroll
        for (int k2 = 0; k2 < 2; ++k2)
          acc[m + 4][n + 2] = mfma16x32(af1[m][k2], bf1[n][k2], acc[m + 4][n + 2]);
    __builtin_amdgcn_s_setprio(0);
    VMCNT6();
    BAR();
  }

  asm volatile("s_waitcnt vmcnt(0)" ::: "memory");  // drain tail garbage loads

  // ---- epilogue: D row = g*4+r, col = li (m89-verified layout) ----
#pragma unroll
  for (int m = 0; m < 8; ++m)
#pragma unroll
    for (int n = 0; n < 4; ++n)
#pragma unroll
      for (int r = 0; r < 4; ++r) {
        const int row = bm + wm * 128 + m * 16 + g * 4 + r;
        const int col = bn + wn * 64 + n * 16 + li;
        C[(size_t)row * N + col] = (OutT)acc[m][n][r];
      }
}

// ---------------- 3. causal flash attention + fused 2D RoPE, pipelined -----
// 1 block = 1 (b,h), 512 threads = 8 waves. Wave w owns q-row blocks
// (w, 15-w): balanced causal work.
// Staging pipeline per k-tile kt: {issue V(kt+1) gload -> Vt[kt+1 & 1];
// load K(kt+1) -> regs; COMPUTE(kt); raw s_barrier (no vmcnt drain!);
// rope+ds_write K(kt+1) -> Ks; vmcnt(0)+lgkmcnt(0); s_barrier}.
// Softmax: DPP row_ror{1,2,4,8} reduces (VALU-only; full 16-lane coverage
// via rotation composition); skip-identity rescale (when mx <= mold the
// old path multiplied by exp2(0)==1.0 -- exact skip); 1/sqrt(d) folded
// into Q-rope.
//   Ks: row-major [64][128], 16B chunk c at phys c^(key&7) (conflict-free).
//   Vt: 2 x row-major [64 key][128 d], same chunk swizzle, async gload16;
//       PV B-frags via ds_read_b64_tr_b16 (m156 model, R9-verified).
//   Ps: per-wave P round-trip (D-frag -> A-frag layout), stride 40.
__global__ void __launch_bounds__(512)
attn_kernel(const _Float16* __restrict__ qkv, _Float16* __restrict__ O,
            const int* __restrict__ positions) {
  const int b  = blockIdx.x >> 4;
  const int h  = blockIdx.x & 15;
  const int tb = b << 8;
  const int tid = threadIdx.x;
  const int lane = tid & 63;
  const int w = tid >> 6;
  const int g = lane >> 4, li = lane & 15;

  __shared__ __attribute__((aligned(16))) _Float16 Ks[64 * 128];
  __shared__ __attribute__((aligned(16))) _Float16 Vt[2][64 * 128];
  __shared__ __attribute__((aligned(16))) _Float16 Ps[8][32 * 40];
  __shared__ float2 tab[512];
  __shared__ int    ptab[256];

  // ---- staging helpers ----
  auto issueV = [&](int kt, int vb) {
#pragma unroll
    for (int i = 0; i < 2; ++i) {
      const int s = i * 512 + tid;
      const int key = s >> 4;
      const int sch = (s & 15) ^ (key & 7);
      gload16(qkv + (size_t)(tb + kt * 64 + key) * 6144 + 4096 + h * 128 + sch * 8,
              (char*)Vt[vb] + (i * 512 + (tid & ~63)) * 16);
    }
  };

  f16x8 kreg[2];
  auto loadK = [&](int kt) {
#pragma unroll
    for (int i = 0; i < 2; ++i) {
      const int s = i * 512 + tid;
      const int key = s >> 4;
      const int c = s & 15;
      kreg[i] = *(const f16x8*)(qkv + (size_t)(tb + kt * 64 + key) * 6144
                                + 2048 + h * 128 + c * 8);
    }
  };
  auto ropeWriteK = [&](int kt) {
#pragma unroll
    for (int i = 0; i < 2; ++i) {
      const int s = i * 512 + tid;
      const int key = s >> 4;
      const int c = s & 15;   // logical 16B chunk (4 rope pairs)
      const int pos = ptab[kt * 64 + key];
      const f16x8 v = kreg[i];
      f16x8 o;
      if (pos == 0) {
#pragma unroll
        for (int u = 0; u < 8; ++u) o[u] = (_Float16)0.f;
      } else {
        const int iv = (pos - 1) >> 4, jv = (pos - 1) & 15;
        const int tv = (c < 8) ? iv : jv;    // d2 = c*4+u < 32 <=> c<8
#pragma unroll
        for (int u = 0; u < 4; ++u) {
          const float2 cs = tab[tv * 32 + ((c * 4 + u) & 31)];
          const float x0 = (float)v[2 * u], x1 = (float)v[2 * u + 1];
          o[2 * u]     = (_Float16)(x0 * cs.x - x1 * cs.y);
          o[2 * u + 1] = (_Float16)(x1 * cs.x + x0 * cs.y);
        }
      }
      *(f16x8*)((char*)Ks + key * 256 + (c ^ (key & 7)) * 16) = o;
    }
  };

  // ---- prologue: V(0) in flight under table build + Q rope ----
  issueV(0, 0);
  {
    const float ang = (float)(tid >> 5) * exp2f((float)(tid & 31) * NLOG2B_32);
    float s, c;
    sincosf(ang, &s, &c);
    tab[tid] = make_float2(c, s);
    if (tid < 256) ptab[tid] = positions[tb + tid];
  }
  asm volatile("s_waitcnt lgkmcnt(0)" ::: "memory");
  BAR();   // tab/ptab visible; V(0) gloads still in flight

  const int qb[2]   = {w, 15 - w};
  const int qrow[2] = {qb[0] * 16, qb[1] * 16};
  const int kmax[2] = {qb[0] >> 2, qb[1] >> 2};

  // tr-read per-lane constants: li = jj*4 + cc
  const int jj = li >> 2;
  const int cc = li & 3;
  const unsigned vbase =
      (unsigned)(unsigned long long)(__attribute__((address_space(3))) _Float16*)Vt;

  const float scale = 0.08838834764831845f;  // 1/sqrt(128), folded into Q

  // ---- load Q + rope in registers (scale folded) ----
  f16x8 qf[2][4];
#pragma unroll
  for (int rb = 0; rb < 2; ++rb) {
    const int pos = ptab[qrow[rb] + li];
    const int iv = (pos - 1) >> 4, jv = (pos - 1) & 15;
#pragma unroll
    for (int ks = 0; ks < 4; ++ks) {
      f16x8 v = *(const f16x8*)(qkv + (size_t)(tb + qrow[rb] + li) * 6144
                                + h * 128 + ks * 32 + g * 8);
      f16x8 o;
      if (pos == 0) {
#pragma unroll
        for (int u = 0; u < 8; ++u) o[u] = (_Float16)0.f;
      } else {
        const int tv = (ks < 2) ? iv : jv;   // d2 = ks*16+g*4+u < 32 <=> ks<2
#pragma unroll
        for (int u = 0; u < 4; ++u) {
          const float2 cs = tab[tv * 32 + ((ks * 16 + g * 4 + u) & 31)];
          const float x0 = (float)v[2 * u] * scale;
          const float x1 = (float)v[2 * u + 1] * scale;
          o[2 * u]     = (_Float16)(x0 * cs.x - x1 * cs.y);
          o[2 * u + 1] = (_Float16)(x1 * cs.x + x0 * cs.y);
        }
      }
      qf[rb][ks] = o;
    }
  }

  loadK(0);
  ropeWriteK(0);
  asm volatile("s_waitcnt vmcnt(0) lgkmcnt(0)" ::: "memory");
  BAR();   // Ks(0) + Vt[0] ready

  f32x4 oacc[2][8] = {};
  float m_r[2][4], l_r[2][4];
#pragma unroll
  for (int rb = 0; rb < 2; ++rb)
#pragma unroll
    for (int r = 0; r < 4; ++r) { m_r[rb][r] = -1e30f; l_r[rb][r] = 0.f; }

  for (int kt = 0; kt < 4; ++kt) {
    const int vb = kt & 1;
    if (kt < 3) {                  // pipeline: next tile's loads in flight
      issueV(kt + 1, vb ^ 1);
      loadK(kt + 1);
    }

    const bool act[2] = {kt <= kmax[0], kt <= kmax[1]};
    if (act[0] || act[1]) {
      // ---- S = Q K^T (64 keys; scale pre-applied to Q) ----
      f32x4 sacc[2][4] = {};
#pragma unroll
      for (int ks = 0; ks < 4; ++ks) {
        f16x8 kf[4];
#pragma unroll
        for (int cb = 0; cb < 4; ++cb) {
          const int key = cb * 16 + li;
          const int chunk = (ks * 4 + g) ^ (key & 7);
          kf[cb] = *(const f16x8*)((const char*)Ks + key * 256 + chunk * 16);
        }
#pragma unroll
        for (int rb = 0; rb < 2; ++rb)
          if (act[rb])
#pragma unroll
            for (int cb = 0; cb < 4; ++cb)
              sacc[rb][cb] = mfma16x32(qf[rb][ks], kf[cb], sacc[rb][cb]);
      }
      // ---- online softmax (DPP row_ror reduces, skip-identity rescale) ----
#pragma unroll
      for (int rb = 0; rb < 2; ++rb) {
        if (!act[rb]) continue;
#pragma unroll
        for (int r = 0; r < 4; ++r) {
          const int q = qrow[rb] + g * 4 + r;
          float mx = -1e30f;
#pragma unroll
          for (int cb = 0; cb < 4; ++cb) {
            float sv = sacc[rb][cb][r];
            const int key = kt * 64 + cb * 16 + li;
            sv = (key <= q) ? sv : -1e30f;
            sacc[rb][cb][r] = sv;
            mx = fmaxf(mx, sv);
          }
          mx = fmaxf(mx, dppror<0x121>(mx));
          mx = fmaxf(mx, dppror<0x122>(mx));
          mx = fmaxf(mx, dppror<0x124>(mx));
          mx = fmaxf(mx, dppror<0x128>(mx));
          const float mold = m_r[rb][r];
          float alpha = 1.f;
          if (mx > mold) {        // uniform within 16-lane group
            m_r[rb][r] = mx;
            alpha = exp2f((mold - mx) * LOG2E);
#pragma unroll
            for (int db = 0; db < 8; ++db)
              oacc[rb][db][r] *= alpha;
          }
          const float mnew = m_r[rb][r];
          float rsum = 0.f;
#pragma unroll
          for (int cb = 0; cb < 4; ++cb) {
            const float pv = exp2f((sacc[rb][cb][r] - mnew) * LOG2E);
            sacc[rb][cb][r] = pv;
            rsum += pv;
          }
          rsum += dppror<0x121>(rsum);
          rsum += dppror<0x122>(rsum);
          rsum += dppror<0x124>(rsum);
          rsum += dppror<0x128>(rsum);
          l_r[rb][r] = l_r[rb][r] * alpha + rsum;
        }
      }
      // ---- O += P V, two 32-key halves; V frags via ds_read_b64_tr_b16 ----
#pragma unroll
      for (int ks2 = 0; ks2 < 2; ++ks2) {
#pragma unroll
        for (int rb = 0; rb < 2; ++rb) {
          if (!act[rb]) continue;
#pragma unroll
          for (int cbh = 0; cbh < 2; ++cbh) {
            const int cb = ks2 * 2 + cbh;
#pragma unroll
            for (int r = 0; r < 4; ++r)
              Ps[w][(rb * 16 + g * 4 + r) * 40 + cbh * 16 + li] =
                  (_Float16)sacc[rb][cb][r];
          }
        }
        asm volatile("s_waitcnt lgkmcnt(0)" ::: "memory");
        f16x8 pa[2];
#pragma unroll
        for (int rb = 0; rb < 2; ++rb)
          if (act[rb])
            pa[rb] = *(const f16x8*)(&Ps[w][(rb * 16 + li) * 40 + g * 8]);

        // V B-frags: rows ks2*32+g*8+jj (+4), d-window db*16, swizzled chunks
        f16x4 vlo[8], vhi[8];
        const int rowA = ks2 * 32 + g * 8 + jj;
        const unsigned base1 = vbase + (unsigned)(vb * 16384)
                             + (unsigned)(rowA * 256 + (cc & 1) * 8);
        const unsigned base2 = base1 + 4 * 256;
#pragma unroll
        for (int db = 0; db < 8; ++db) {
          const int ch = db * 2 + (cc >> 1);
          const unsigned a1 = base1 + (unsigned)((ch ^ jj) << 4);
          const unsigned a2 = base2 + (unsigned)((ch ^ jj ^ 4) << 4);
          asm volatile("ds_read_b64_tr_b16 %0, %1" : "=v"(vlo[db]) : "v"(a1));
          asm volatile("ds_read_b64_tr_b16 %0, %1" : "=v"(vhi[db]) : "v"(a2));
        }
        asm volatile("s_waitcnt lgkmcnt(0)" ::: "memory");
        __builtin_amdgcn_sched_barrier(0);
#pragma unroll
        for (int db = 0; db < 8; ++db) {
          const f16x8 vf = __builtin_shufflevector(vlo[db], vhi[db],
                                                   0, 1, 2, 3, 4, 5, 6, 7);
#pragma unroll
          for (int rb = 0; rb < 2; ++rb)
            if (act[rb])
              oacc[rb][db] = mfma16x32(pa[rb], vf, oacc[rb][db]);
        }
      }
    }

    // BAR_a: all waves done reading Ks(kt); own ds reads already consumed,
    // V(kt+1) gloads stay in flight (no vmcnt drain on raw s_barrier).
    BAR();
    if (kt < 3) ropeWriteK(kt + 1);
    asm volatile("s_waitcnt vmcnt(0) lgkmcnt(0)" ::: "memory");
    BAR();   // Ks(kt+1) visible + V(kt+1) landed
  }

  // ---- epilogue: O / l ----
#pragma unroll
  for (int rb = 0; rb < 2; ++rb)
#pragma unroll
    for (int db = 0; db < 8; ++db)
#pragma unroll
      for (int r = 0; r < 4; ++r) {
        const int row = tb + qrow[rb] + g * 4 + r;
        const int col = h * 128 + db * 16 + li;
        O[(size_t)row * 2048 + col] = (_Float16)(oacc[rb][db][r] / l_r[rb][r]);
      }
}

// ---------------------------------------------------------------------------
extern "C" void kernel_launch(void* const* d_in, const int* in_sizes, int n_in,
                              void* d_out, int out_size, void* d_ws, size_t ws_size,
                              hipStream_t stream) {
  const float* x         = (const float*)d_in[0];
  const int*   positions = (const int*)d_in[1];
  const float* wqkv      = (const float*)d_in[2];
  const float* wo        = (const float*)d_in[3];
  float* out = (float*)d_out;

  char* ws = (char*)d_ws;
  _Float16* qkv    = (_Float16*)(ws);                    // 100663296 B
  _Float16* xf     = (_Float16*)(ws + 100663296);        //  33554432 B
  _Float16* wqkvf  = (_Float16*)(ws + 134217728);        //  25165824 B
  _Float16* wof    = (_Float16*)(ws + 159383552);        //   8388608 B
  _Float16* of     = xf;  // reuse x region for attention output

  cvt3_f32_f16<<<32768, 256, 0, stream>>>(x, xf, wqkv, wqkvf, wo, wof);

  gemm_bt5<_Float16><<<768, 512, 0, stream>>>(xf, wqkvf, qkv, 8192, 6144, 2048);

  attn_kernel<<<512, 512, 0, stream>>>(qkv, of, positions);

  gemm_bt5<float><<<256, 512, 0, stream>>>(of, wof, out, 8192, 2048, 2048);
}